// Round 4
// baseline (227.945 us; speedup 1.0000x reference)
//
#include <hip/hip_runtime.h>
#include <cmath>

#define NT 144

typedef float v2f __attribute__((ext_vector_type(2)));

// P(a,x) = n * x^a * e^-x / (d1 * Gamma(a+1)); n via 18-term rational Horner
// with x-independent denominators d_k (named scalars). All per-element
// transcendentals replaced by full-rate polynomial sequences (packed 2-wide):
//   log2: musl bit reduction (m in [sqrt2/2, sqrt2)) + Cephes deg-8 ln poly
//   exp2: rndne split + Cephes deg-5 poly + bit-built 2^n (underflow -> 0)
// log2(crow) folded into the exponent so the epilogue is 1 fma + 2 mul.

__global__ __launch_bounds__(256) void dynangio_kernel(
    const float* __restrict__ x,
    const float* __restrict__ t,
    const float* __restrict__ alpha,
    const float* __restrict__ R,
    float* __restrict__ out,
    int B)
{
    __shared__ alignas(16) float sh_t[NT];
    __shared__ alignas(16) float sh_re[NT];
    const int tid = threadIdx.x;
    if (tid < NT) {
        sh_t[tid]  = t[tid];
        sh_re[tid] = R[tid] * sinf(alpha[tid] * 0.017453292519943295f);
    }
    __syncthreads();

    const int i = blockIdx.x * blockDim.x + tid;
    if (i >= B) return;

    const float4 xi = reinterpret_cast<const float4*>(x)[i];
    const float dt  = xi.x;
    const float s   = xi.y;
    const float p   = xi.z;
    const float amp = xi.w;

    const float T1B    = 1.65f;
    const float TAU    = 1.8f;
    const float LOG2E  = 1.4426950408889634f;   // == 1/ln2

    const float u  = p * s;            // a-1 in [0,1)
    const float a  = 1.0f + u;
    const float sp = s + (1.0f / T1B);

    // Gamma(1+u), u in [0,1): A&S 6.1.36, |err| <= 3e-7
    float g = 0.035868343f;
    g = g * u - 0.193527818f;
    g = g * u + 0.482199394f;
    g = g * u - 0.756704078f;
    g = g * u + 0.918206857f;
    g = g * u - 0.897056937f;
    g = g * u + 0.988205891f;
    g = g * u - 0.577191652f;
    g = g * u + 1.0f;
    const float Ga1 = (1.0f + u) * g;  // Gamma(a+1)

    // d_k = prod_{m=k..18}(a+m) -- named scalars (VGPRs, no scratch)
    const float d18 = a + 18.0f;
    const float d17 = (a + 17.0f) * d18;
    const float d16 = (a + 16.0f) * d17;
    const float d15 = (a + 15.0f) * d16;
    const float d14 = (a + 14.0f) * d15;
    const float d13 = (a + 13.0f) * d14;
    const float d12 = (a + 12.0f) * d13;
    const float d11 = (a + 11.0f) * d12;
    const float d10 = (a + 10.0f) * d11;
    const float d9  = (a +  9.0f) * d10;
    const float d8  = (a +  8.0f) * d9;
    const float d7  = (a +  7.0f) * d8;
    const float d6  = (a +  6.0f) * d7;
    const float d5  = (a +  5.0f) * d6;
    const float d4  = (a +  4.0f) * d5;
    const float d3  = (a +  3.0f) * d4;
    const float d2  = (a +  2.0f) * d3;
    const float d1  = (a +  1.0f) * d2;

    const float invDG = 1.0f / (d1 * Ga1);

    // SF = 2*exp(-dt/T1B)*(s/sp)^a  (per-row hw transc: amortized /144)
    const float SF = 2.0f * __builtin_amdgcn_exp2f(
        a * (__builtin_amdgcn_logf(s) - __builtin_amdgcn_logf(sp))
        - dt * (LOG2E / T1B));

    const float crow  = amp * SF * invDG;              // >= 0, <= ~1e-17
    const float lc    = __builtin_amdgcn_logf(fmaxf(crow, 1e-38f)); // log2(crow)
    const float nspdt = -sp * dt;
    const float spTau = sp * TAU;

    auto elem = [&](float tj, float rej) -> float {
        const float x1 = __builtin_fmaf(sp, tj, nspdt);  // > 0.48 always
        const float x2 = fmaxf(x1 - spTau, 1e-30f);      // 1e-30 ~ 0 for series
        v2f X; X.x = x1; X.y = x2;

        // packed 18-term Horner: N = X*N + d_k
        v2f N = {1.0f, 1.0f};
        N = X*N + d18;  N = X*N + d17;  N = X*N + d16;
        N = X*N + d15;  N = X*N + d14;  N = X*N + d13;
        N = X*N + d12;  N = X*N + d11;  N = X*N + d10;
        N = X*N + d9;   N = X*N + d8;   N = X*N + d7;
        N = X*N + d6;   N = X*N + d5;   N = X*N + d4;
        N = X*N + d3;   N = X*N + d2;   N = X*N + d1;

        // ---- dual software log2 ----
        const unsigned i1 = __float_as_uint(x1) + 0x004AFB0Du;
        const unsigned i2 = __float_as_uint(x2) + 0x004AFB0Du;
        v2f EF; EF.x = (float)((int)(i1 >> 23) - 127);
                EF.y = (float)((int)(i2 >> 23) - 127);
        v2f T;  T.x  = __uint_as_float((i1 & 0x007FFFFFu) + 0x3F3504F3u) - 1.0f;
                T.y  = __uint_as_float((i2 & 0x007FFFFFu) + 0x3F3504F3u) - 1.0f;
        v2f Z = T * T;
        v2f q = T * 7.0376836292e-2f - 1.1514610310e-1f;
        q = q*T + 1.1676998740e-1f;
        q = q*T - 1.2420140846e-1f;
        q = q*T + 1.4249322787e-1f;
        q = q*T - 1.6668057665e-1f;
        q = q*T + 2.0000714765e-1f;
        q = q*T - 2.4999993993e-1f;
        q = q*T + 3.3333331174e-1f;
        v2f ln = T*(Z*q) - 0.5f*Z;     // ln(1+t) - t
        ln = T + ln;
        v2f L = ln*LOG2E + EF;         // log2(x)

        // Ee = a*log2(x) - x*log2e + log2(crow)
        v2f Ee = lc - X*LOG2E;
        Ee = a*L + Ee;

        // ---- dual software exp2 ----
        const float r1 = __builtin_rintf(Ee.x);
        const float r2 = __builtin_rintf(Ee.y);
        v2f Nr; Nr.x = r1; Nr.y = r2;
        v2f F = Ee - Nr;               // [-0.5, 0.5]
        v2f pe = F * 1.535336188319500e-4f + 1.339887440266574e-3f;
        pe = pe*F + 9.618437357674640e-3f;
        pe = pe*F + 5.550332471162809e-2f;
        pe = pe*F + 2.402264791363012e-1f;
        pe = pe*F + 6.931472028550421e-1f;
        v2f tf = pe*F + 1.0f;          // 2^F
        const int n1i = (int)r1, n2i = (int)r2;
        const int b1 = n1i + 127, b2 = n2i + 127;
        const float sc1 = __uint_as_float((unsigned)(b1 > 0 ? b1 : 0) << 23);
        const float sc2 = __uint_as_float((unsigned)(b2 > 0 ? b2 : 0) << 23);
        const float e1 = tf.x * sc1;   // crow * x1^a * e^-x1 (scaled)
        const float e2 = tf.y * sc2;

        const float gg = __builtin_fmaf(N.x, e1, -(N.y * e2));
        return rej * gg;
    };

    float* __restrict__ orow = out + (size_t)i * NT;
    const float4* sh_t4  = reinterpret_cast<const float4*>(sh_t);
    const float4* sh_re4 = reinterpret_cast<const float4*>(sh_re);

    #pragma unroll 1
    for (int jb = 0; jb < NT / 4; ++jb) {
        const float4 tj4 = sh_t4[jb];
        const float4 re4 = sh_re4[jb];
        float4 res;
        res.x = elem(tj4.x, re4.x);
        res.y = elem(tj4.y, re4.y);
        res.z = elem(tj4.z, re4.z);
        res.w = elem(tj4.w, re4.w);
        reinterpret_cast<float4*>(orow)[jb] = res;
    }
}

extern "C" void kernel_launch(void* const* d_in, const int* in_sizes, int n_in,
                              void* d_out, int out_size, void* d_ws, size_t ws_size,
                              hipStream_t stream) {
    const float* x     = (const float*)d_in[0];
    const float* t     = (const float*)d_in[1];
    const float* alpha = (const float*)d_in[2];
    const float* R     = (const float*)d_in[3];
    float* out = (float*)d_out;

    const int B = in_sizes[0] / 4;
    const int threads = 256;
    const int blocks = (B + threads - 1) / threads;
    hipLaunchKernelGGL(dynangio_kernel, dim3(blocks), dim3(threads), 0, stream,
                       x, t, alpha, R, out, B);
}

// Round 5
// 173.703 us; speedup vs baseline: 1.3123x; 1.3123x over previous
//
#include <hip/hip_runtime.h>
#include <cmath>

#define NT 144

typedef float v2f __attribute__((ext_vector_type(2)));

// Round-3 math (18-term rational Horner, packed v_pk_fma_f32, HW v_log/v_exp)
// with a coalescing-friendly work map:
//   4 threads per row: c = tid&3, row = blockIdx.x*64 + (tid>>2)
//   thread's j-chunks = {c + 4k, k=0..8}  (float4 chunks)
// A wave's store covers 16 rows x 64 B (4 lanes contiguous), successive k fill
// adjacent 64-B halves of the same 128-B L2 lines -> writes fully merge.
// Grid = B/64 = 4096 blocks (4x round-4) for occupancy.

__global__ __launch_bounds__(256) void dynangio_kernel(
    const float* __restrict__ x,
    const float* __restrict__ t,
    const float* __restrict__ alpha,
    const float* __restrict__ R,
    float* __restrict__ out,
    int B)
{
    __shared__ alignas(16) float sh_t[NT];
    __shared__ alignas(16) float sh_re[NT];
    const int tid = threadIdx.x;
    if (tid < NT) {
        sh_t[tid]  = t[tid];
        sh_re[tid] = R[tid] * sinf(alpha[tid] * 0.017453292519943295f);
    }
    __syncthreads();

    const int c   = tid & 3;          // which j-chunk phase
    const int row = blockIdx.x * 64 + (tid >> 2);
    if (row >= B) return;

    const float4 xi = reinterpret_cast<const float4*>(x)[row];
    const float dt  = xi.x;
    const float s   = xi.y;
    const float p   = xi.z;
    const float amp = xi.w;

    const float T1B   = 1.65f;
    const float TAU   = 1.8f;
    const float LOG2E = 1.4426950408889634f;

    const float u  = p * s;            // a-1 in [0,1)
    const float a  = 1.0f + u;
    const float sp = s + (1.0f / T1B);

    // Gamma(1+u), u in [0,1): A&S 6.1.36, |err| <= 3e-7
    float g = 0.035868343f;
    g = g * u - 0.193527818f;
    g = g * u + 0.482199394f;
    g = g * u - 0.756704078f;
    g = g * u + 0.918206857f;
    g = g * u - 0.897056937f;
    g = g * u + 0.988205891f;
    g = g * u - 0.577191652f;
    g = g * u + 1.0f;
    const float Ga1 = (1.0f + u) * g;  // Gamma(a+1)

    // d_k = prod_{m=k..18}(a+m) -- named scalars (VGPRs, no scratch)
    const float d18 = a + 18.0f;
    const float d17 = (a + 17.0f) * d18;
    const float d16 = (a + 16.0f) * d17;
    const float d15 = (a + 15.0f) * d16;
    const float d14 = (a + 14.0f) * d15;
    const float d13 = (a + 13.0f) * d14;
    const float d12 = (a + 12.0f) * d13;
    const float d11 = (a + 11.0f) * d12;
    const float d10 = (a + 10.0f) * d11;
    const float d9  = (a +  9.0f) * d10;
    const float d8  = (a +  8.0f) * d9;
    const float d7  = (a +  7.0f) * d8;
    const float d6  = (a +  6.0f) * d7;
    const float d5  = (a +  5.0f) * d6;
    const float d4  = (a +  4.0f) * d5;
    const float d3  = (a +  3.0f) * d4;
    const float d2  = (a +  2.0f) * d3;
    const float d1  = (a +  1.0f) * d2;

    const float invDG = 1.0f / (d1 * Ga1);

    // SF = 2*exp(-dt/T1B)*(s/sp)^a  (per-row hw transc, amortized)
    const float SF = 2.0f * __builtin_amdgcn_exp2f(
        a * (__builtin_amdgcn_logf(s) - __builtin_amdgcn_logf(sp))
        - dt * (LOG2E / T1B));

    const float crow  = amp * SF * invDG;
    const float nspdt = -sp * dt;
    const float spTau = sp * TAU;

    auto elem = [&](float tj, float rej) -> float {
        const float x1 = __builtin_fmaf(sp, tj, nspdt);   // > 0.48 always
        const float x2 = fmaxf(x1 - spTau, 0.0f);
        v2f X; X.x = x1; X.y = x2;
        v2f N = {1.0f, 1.0f};
        // packed Horner: N = X*N + d_k   (v_pk_fma_f32)
        N = X*N + d18;  N = X*N + d17;  N = X*N + d16;
        N = X*N + d15;  N = X*N + d14;  N = X*N + d13;
        N = X*N + d12;  N = X*N + d11;  N = X*N + d10;
        N = X*N + d9;   N = X*N + d8;   N = X*N + d7;
        N = X*N + d6;   N = X*N + d5;   N = X*N + d4;
        N = X*N + d3;   N = X*N + d2;   N = X*N + d1;
        // x^a * e^-x = exp2(a*log2(x) - x*log2e);  x2==0 -> exp2(-inf)=0
        v2f L; L.x = __builtin_amdgcn_logf(x1); L.y = __builtin_amdgcn_logf(x2);
        v2f Ee = a * L - X * LOG2E;                       // packed fma
        const float e1 = __builtin_amdgcn_exp2f(Ee.x);
        const float e2 = __builtin_amdgcn_exp2f(Ee.y);
        const float gg = __builtin_fmaf(N.x, e1, -(N.y * e2));
        return (crow * rej) * gg;
    };

    float4* __restrict__ orow4 = reinterpret_cast<float4*>(out + (size_t)row * NT);
    const float4* sh_t4  = reinterpret_cast<const float4*>(sh_t);
    const float4* sh_re4 = reinterpret_cast<const float4*>(sh_re);

    #pragma unroll 3
    for (int k = 0; k < 9; ++k) {
        const int ch = c + 4 * k;             // chunk index 0..35
        const float4 tj4 = sh_t4[ch];
        const float4 re4 = sh_re4[ch];
        float4 res;
        res.x = elem(tj4.x, re4.x);
        res.y = elem(tj4.y, re4.y);
        res.z = elem(tj4.z, re4.z);
        res.w = elem(tj4.w, re4.w);
        orow4[ch] = res;
    }
}

extern "C" void kernel_launch(void* const* d_in, const int* in_sizes, int n_in,
                              void* d_out, int out_size, void* d_ws, size_t ws_size,
                              hipStream_t stream) {
    const float* x     = (const float*)d_in[0];
    const float* t     = (const float*)d_in[1];
    const float* alpha = (const float*)d_in[2];
    const float* R     = (const float*)d_in[3];
    float* out = (float*)d_out;

    const int B = in_sizes[0] / 4;
    const int rows_per_block = 64;
    const int blocks = (B + rows_per_block - 1) / rows_per_block;
    hipLaunchKernelGGL(dynangio_kernel, dim3(blocks), dim3(256), 0, stream,
                       x, t, alpha, R, out, B);
}